// Round 1
// 361.972 us; speedup vs baseline: 1.1502x; 1.1502x over previous
//
#include <hip/hip_runtime.h>
#include <hip/hip_bf16.h>
#include <hip/hip_cooperative_groups.h>

// ---- problem constants ----
#define NW 5
#define KS 5
#define SEQ 196
#define DIM 384
#define NSUP 25        // NW*KS support images
#define NQRY 75        // query images
#define NIMG 100       // NSUP + NQRY
#define LSUP 4900      // NSUP*SEQ support rows
#define LSUP_PAD 4992  // 39*128, zero-padded K rows
#define QROWS 208      // padded qs rows per image (13*16)
#define BLOCK_W 980    // KS*SEQ rows per class block
#define OPT_STEPS 15

static constexpr float TEMP_F = 0.0510310363f;
static constexpr float INV_T  = 1.0f / TEMP_F;   // ~19.5959
static constexpr float LR_F   = 0.1f;

typedef short v8s __attribute__((ext_vector_type(8)));   // 8 x bf16 frag (4 VGPRs)
typedef float v4f __attribute__((ext_vector_type(4)));   // 4 x f32 acc

__device__ inline unsigned short f2bf(float x) {
    unsigned int u = __float_as_uint(x);
    u += 0x7fffu + ((u >> 16) & 1u);
    return (unsigned short)(u >> 16);
}

// ---------------------------------------------------------------------------
// Kernel 1a: K-side normalize (pre-scaled by 1/T), rows >= LSUP -> zeros.
// ---------------------------------------------------------------------------
__global__ __launch_bounds__(128) void norm_k(const float* __restrict__ src,
                                              unsigned short* __restrict__ dst) {
    int row = blockIdx.x;
    unsigned short* out = dst + (size_t)row * DIM;
    int t = threadIdx.x;
    if (row >= LSUP) {
        out[t] = 0; out[t + 128] = 0; out[t + 256] = 0;
        return;
    }
    const float* in = src + (size_t)row * DIM;
    float x0 = in[t], x1 = in[t + 128], x2 = in[t + 256];
    float s = x0 * x0 + x1 * x1 + x2 * x2;
    #pragma unroll
    for (int off = 32; off; off >>= 1) s += __shfl_down(s, off);
    __shared__ float wsum[2];
    if ((t & 63) == 0) wsum[t >> 6] = s;
    __syncthreads();
    float sc = INV_T / fmaxf(sqrtf(wsum[0] + wsum[1]), 1e-8f);
    out[t]       = f2bf(x0 * sc);
    out[t + 128] = f2bf(x1 * sc);
    out[t + 256] = f2bf(x2 * sc);
}

// ---------------------------------------------------------------------------
// Kernel 1b: Q-side normalize into padded [100][208][384] buffer.
// img<25: support_emb_query; img>=25: query_emb. Rows 196..207 -> zeros.
// ---------------------------------------------------------------------------
__global__ __launch_bounds__(128) void norm_q(const float* __restrict__ supq,
                                              const float* __restrict__ qry,
                                              unsigned short* __restrict__ dst) {
    int r = blockIdx.x;     // 0..207
    int img = blockIdx.y;   // 0..99
    unsigned short* out = dst + ((size_t)img * QROWS + r) * DIM;
    int t = threadIdx.x;
    if (r >= SEQ) {
        out[t] = 0; out[t + 128] = 0; out[t + 256] = 0;
        return;
    }
    const float* in = (img < NSUP)
        ? supq + ((size_t)img * SEQ + r) * DIM
        : qry  + ((size_t)(img - NSUP) * SEQ + r) * DIM;
    float x0 = in[t], x1 = in[t + 128], x2 = in[t + 256];
    float s = x0 * x0 + x1 * x1 + x2 * x2;
    #pragma unroll
    for (int off = 32; off; off >>= 1) s += __shfl_down(s, off);
    __shared__ float wsum[2];
    if ((t & 63) == 0) wsum[t >> 6] = s;
    __syncthreads();
    float sc = 1.0f / fmaxf(sqrtf(wsum[0] + wsum[1]), 1e-8f);
    out[t]       = f2bf(x0 * sc);
    out[t + 128] = f2bf(x1 * sc);
    out[t + 256] = f2bf(x2 * sc);
}

// ---------------------------------------------------------------------------
// Kernel 2: MFMA fused exp-sum GEMM, global_load_lds staging + XOR swizzle.
//   Rall[img][ls] = sum_qs exp( (Kn[ls] . Qimg[qs]) / T )
// LDS layout: linear [rows][64] bf16 with slot' = slot ^ (row&7) swizzle
// applied on the GLOBAL source side (pre-swizzled per-lane address) and on
// the ds_read side — linear dest as global_load_lds requires (rule #21).
// ---------------------------------------------------------------------------
#define MT  128
#define NTP 208
#define NTT 13
#define KCC 64

__device__ __forceinline__ void gload16(const void* g, void* l) {
    __builtin_amdgcn_global_load_lds(
        (__attribute__((address_space(1))) void*)g,
        (__attribute__((address_space(3))) void*)l, 16, 0, 0);
}

__global__ __launch_bounds__(256, 3) void fused_expsum_mfma(
    const unsigned short* __restrict__ Kb,     // [4992][384] bf16, pre /T
    const unsigned short* __restrict__ Qall,   // [100][208][384] bf16
    float* __restrict__ Rall)
{
    __shared__ __align__(16) unsigned short Asm[MT * KCC];    // 16 KiB
    __shared__ __align__(16) unsigned short Bsm[NTP * KCC];   // 26 KiB

    int t = threadIdx.x;
    int img = blockIdx.y;
    int m_base = blockIdx.x * MT;
    const unsigned short* Qimg = Qall + (size_t)img * (QROWS * DIM);

    int wv = t >> 6;        // wave 0..3
    int l  = t & 63;
    int lo = l & 15;        // MFMA frag row/col index
    int hi = l >> 4;        // k-group

    // staging: each global_load_lds writes 1024B = 8 rows x 128B, linear.
    // lane l covers (row = l>>3, 16B slot = l&7); source k-slot pre-swizzled.
    int srow = l >> 3;
    int skp  = (l & 7) ^ srow;      // involution within 8-slot row
    const unsigned short* aSrc = Kb   + (size_t)(m_base + wv * 32 + srow) * DIM + skp * 8;
    const unsigned short* bSrc = Qimg + (size_t)srow * DIM + skp * 8;

    v4f acc0[NTT], acc1[NTT];
    #pragma unroll
    for (int n = 0; n < NTT; ++n) {
        acc0[n] = (v4f){0.f, 0.f, 0.f, 0.f};
        acc1[n] = (v4f){0.f, 0.f, 0.f, 0.f};
    }

    for (int kb = 0; kb < DIM; kb += KCC) {
        // A: wave wv stages rows [wv*32, wv*32+32) as 4 x 8-row groups
        #pragma unroll
        for (int j = 0; j < 4; ++j)
            gload16(aSrc + (size_t)j * 8 * DIM + kb,
                    Asm + (wv * 32 + j * 8) * KCC);
        // B: 26 8-row groups round-robined over 4 waves
        #pragma unroll
        for (int jj = 0; jj < 7; ++jj) {
            int j = wv + jj * 4;
            if (j < 26)
                gload16(bSrc + (size_t)j * 8 * DIM + kb,
                        Bsm + j * 8 * KCC);
        }
        __syncthreads();   // drains vmcnt before LDS reads

        const unsigned short* Ar0 = Asm + (wv * 32 + lo) * KCC;
        const unsigned short* Br  = Bsm + lo * KCC;
        #pragma unroll
        for (int kk = 0; kk < 2; ++kk) {
            int koff = ((hi + 4 * kk) ^ (lo & 7)) * 8;   // swizzled k-slot
            v8s a0 = *(const v8s*)(Ar0 + koff);
            v8s a1 = *(const v8s*)(Ar0 + 16 * KCC + koff);
            #pragma unroll
            for (int n = 0; n < NTT; ++n) {
                v8s bb = *(const v8s*)(Br + n * 16 * KCC + koff);
                acc0[n] = __builtin_amdgcn_mfma_f32_16x16x32_bf16(a0, bb, acc0[n], 0, 0, 0);
                acc1[n] = __builtin_amdgcn_mfma_f32_16x16x32_bf16(a1, bb, acc1[n], 0, 0, 0);
            }
        }
        __syncthreads();
    }

    // epilogue: exp + sum over cols. C/D layout: col=lo, row=hi*4+reg.
    float s0[4] = {0.f, 0.f, 0.f, 0.f}, s1[4] = {0.f, 0.f, 0.f, 0.f};
    #pragma unroll
    for (int n = 0; n < NTT; ++n) {
        bool ok = (n * 16 + lo) < SEQ;
        #pragma unroll
        for (int j = 0; j < 4; ++j) {
            s0[j] += ok ? __expf(acc0[n][j]) : 0.f;
            s1[j] += ok ? __expf(acc1[n][j]) : 0.f;
        }
    }
    #pragma unroll
    for (int m = 1; m < 16; m <<= 1) {
        #pragma unroll
        for (int j = 0; j < 4; ++j) {
            s0[j] += __shfl_xor(s0[j], m);
            s1[j] += __shfl_xor(s1[j], m);
        }
    }
    if (lo == 0) {
        #pragma unroll
        for (int j = 0; j < 4; ++j) {
            int r0 = m_base + wv * 32 + hi * 4 + j;
            int r1 = r0 + 16;
            if (r0 < LSUP) {
                float o = s0[j];
                if (img < NSUP && (r0 / SEQ) == img) o = 0.f;
                Rall[(size_t)img * LSUP + r0] = o;
            }
            if (r1 < LSUP) {
                float o = s1[j];
                if (img < NSUP && (r1 / SEQ) == img) o = 0.f;
                Rall[(size_t)img * LSUP + r1] = o;
            }
        }
    }
}

// ---------------------------------------------------------------------------
// Kernel 3: fused optimizer (init + 15 SGD steps + final prediction).
// Cooperative launch: 10 blocks (5 classes x 2 halves) x 512 threads.
// Thread owns one ls row; its 25 R values live in registers for all steps.
// Dbufs (16*125) and out (375) are pre-zeroed via hipMemsetAsync.
// Reduction topology matches the previous opt_step exactly (8-wave shfl +
// LDS + per-(b,w) atomic), so D sums are numerically identical.
// ---------------------------------------------------------------------------
__global__ __launch_bounds__(512) void opt_fused(
    const float* __restrict__ Rall,
    const int* __restrict__ labels,
    float* __restrict__ Dbufs,      // [16][125], pre-zeroed
    float* __restrict__ out)        // [75][5], pre-zeroed
{
    cooperative_groups::grid_group grid = cooperative_groups::this_grid();
    __shared__ float cfs[NSUP];
    __shared__ float red[8][NSUP];

    int blk = blockIdx.x;           // 0..9
    int w = blk >> 1, h = blk & 1;
    int t = threadIdx.x;
    int wave = t >> 6, lane = t & 63;
    int li = h * 490 + t;
    bool act = t < 490;
    int ls = w * BLOCK_W + li;

    float Rv[NSUP];
    #pragma unroll
    for (int b = 0; b < NSUP; ++b)
        Rv[b] = act ? Rall[(size_t)b * LSUP + ls] : 0.f;

    float vv = 0.f;
    float e  = 1.f;                 // e^{v/T}, v starts at 0

    // ---- D0 contribution (e = 1) ----
    {
        float part[NSUP];
        #pragma unroll
        for (int b = 0; b < NSUP; ++b) part[b] = Rv[b];
        #pragma unroll
        for (int b = 0; b < NSUP; ++b) {
            #pragma unroll
            for (int m = 32; m; m >>= 1) part[b] += __shfl_xor(part[b], m);
        }
        if (lane == 0) {
            #pragma unroll
            for (int b = 0; b < NSUP; ++b) red[wave][b] = part[b];
        }
        __syncthreads();
        if (t < NSUP) {
            float s = 0.f;
            #pragma unroll
            for (int wv2 = 0; wv2 < 8; ++wv2) s += red[wv2][t];
            atomicAdd(&Dbufs[t * 5 + w], s);
        }
    }
    grid.sync();

    // ---- SGD steps ----
    for (int s = 0; s < OPT_STEPS; ++s) {
        const float* Dp = Dbufs + s * 125;
        if (t < NSUP) {
            int b = t;
            float Dsum = 0.f, Dw = 1.f;
            #pragma unroll
            for (int ww = 0; ww < 5; ++ww) {
                float d = Dp[b * 5 + ww];
                Dsum += d;
                if (ww == w) Dw = d;
            }
            int y = labels[b];
            cfs[b] = ((Dw / Dsum) - (w == y ? 1.f : 0.f)) * (INV_T / 25.f) / Dw;
        }
        __syncthreads();
        float g = 0.f;
        #pragma unroll
        for (int b = 0; b < NSUP; ++b) g += cfs[b] * Rv[b];
        if (act) {
            vv -= LR_F * e * g;
            e = __expf(vv * INV_T);
        }
        float part[NSUP];
        #pragma unroll
        for (int b = 0; b < NSUP; ++b) part[b] = e * Rv[b];   // inactive: Rv=0
        #pragma unroll
        for (int b = 0; b < NSUP; ++b) {
            #pragma unroll
            for (int m = 32; m; m >>= 1) part[b] += __shfl_xor(part[b], m);
        }
        if (lane == 0) {
            #pragma unroll
            for (int b = 0; b < NSUP; ++b) red[wave][b] = part[b];
        }
        __syncthreads();
        if (t < NSUP) {
            float s2 = 0.f;
            #pragma unroll
            for (int wv2 = 0; wv2 < 8; ++wv2) s2 += red[wv2][t];
            atomicAdd(&Dbufs[(s + 1) * 125 + t * 5 + w], s2);
        }
        grid.sync();
    }

    // ---- final prediction: out[qb][w] += sum e^{v/T} * R[25+qb][ls] ----
    for (int qb = 0; qb < NQRY; ++qb) {
        float p = act ? e * Rall[(size_t)(NSUP + qb) * LSUP + ls] : 0.f;
        #pragma unroll
        for (int m = 32; m; m >>= 1) p += __shfl_xor(p, m);
        if (lane == 0) atomicAdd(&out[qb * 5 + w], p);
    }
    grid.sync();
    if (blk == 0) {
        for (int i = t; i < NQRY * NW; i += 512) out[i] = logf(out[i]);
    }
}

// ---------------------------------------------------------------------------
extern "C" void kernel_launch(void* const* d_in, const int* in_sizes, int n_in,
                              void* d_out, int out_size, void* d_ws, size_t ws_size,
                              hipStream_t stream) {
    const float* sup_key = (const float*)d_in[0];   // [25,196,384]
    const float* sup_qry = (const float*)d_in[1];   // [25,196,384]
    const float* qry     = (const float*)d_in[2];   // [75,196,384]
    const int*   labels  = (const int*)d_in[3];     // [25]
    float* out = (float*)d_out;                     // [75,5]

    char* ws = (char*)d_ws;
    size_t off = 0;
    auto take = [&](size_t bytes) {
        char* p = ws + off;
        off = (off + bytes + 255) & ~(size_t)255;
        return p;
    };
    unsigned short* Kb   = (unsigned short*)take((size_t)LSUP_PAD * DIM * 2);
    unsigned short* Qall = (unsigned short*)take((size_t)NIMG * QROWS * DIM * 2);
    float*          Rall = (float*)take((size_t)NIMG * LSUP * 4);
    float*          Dbuf = (float*)take((size_t)(OPT_STEPS + 1) * 125 * 4);

    hipMemsetAsync(Dbuf, 0, (size_t)(OPT_STEPS + 1) * 125 * 4, stream);
    hipMemsetAsync(out, 0, (size_t)NQRY * NW * 4, stream);

    norm_k<<<LSUP_PAD, 128, 0, stream>>>(sup_key, Kb);
    norm_q<<<dim3(QROWS, NIMG), 128, 0, stream>>>(sup_qry, qry, Qall);

    fused_expsum_mfma<<<dim3(LSUP_PAD / MT, NIMG), 256, 0, stream>>>(Kb, Qall, Rall);

    const float* RallArg = Rall;
    const int*   labArg  = labels;
    float*       DbufArg = Dbuf;
    float*       outArg  = out;
    void* kargs[] = {(void*)&RallArg, (void*)&labArg, (void*)&DbufArg, (void*)&outArg};
    hipLaunchCooperativeKernel(opt_fused, dim3(10), dim3(512), kargs, 0, stream);
}

// Round 2
// 256.516 us; speedup vs baseline: 1.6231x; 1.4111x over previous
//
#include <hip/hip_runtime.h>
#include <hip/hip_bf16.h>

// ---- problem constants ----
#define NW 5
#define KS 5
#define SEQ 196
#define DIM 384
#define NSUP 25        // NW*KS support images
#define NQRY 75        // query images
#define NIMG 100       // NSUP + NQRY
#define LSUP 4900      // NSUP*SEQ support rows
#define LSUP_PAD 4992  // 39*128, zero-padded K rows
#define QROWS 208      // padded qs rows per image (13*16)
#define BLOCK_W 980    // KS*SEQ rows per class block
#define OPT_STEPS 15
#define MTILES 39      // LSUP_PAD / MT

static constexpr float TEMP_F = 0.0510310363f;
static constexpr float INV_T  = 1.0f / TEMP_F;   // ~19.5959
static constexpr float LR_F   = 0.1f;

typedef short v8s __attribute__((ext_vector_type(8)));   // 8 x bf16 frag (4 VGPRs)
typedef float v4f __attribute__((ext_vector_type(4)));   // 4 x f32 acc

__device__ inline unsigned short f2bf(float x) {
    unsigned int u = __float_as_uint(x);
    u += 0x7fffu + ((u >> 16) & 1u);
    return (unsigned short)(u >> 16);
}

// ---------------------------------------------------------------------------
// Kernel 1a: K-side normalize (pre-scaled by 1/T), rows >= LSUP -> zeros.
// ---------------------------------------------------------------------------
__global__ __launch_bounds__(128) void norm_k(const float* __restrict__ src,
                                              unsigned short* __restrict__ dst) {
    int row = blockIdx.x;
    unsigned short* out = dst + (size_t)row * DIM;
    int t = threadIdx.x;
    if (row >= LSUP) {
        out[t] = 0; out[t + 128] = 0; out[t + 256] = 0;
        return;
    }
    const float* in = src + (size_t)row * DIM;
    float x0 = in[t], x1 = in[t + 128], x2 = in[t + 256];
    float s = x0 * x0 + x1 * x1 + x2 * x2;
    #pragma unroll
    for (int off = 32; off; off >>= 1) s += __shfl_down(s, off);
    __shared__ float wsum[2];
    if ((t & 63) == 0) wsum[t >> 6] = s;
    __syncthreads();
    float sc = INV_T / fmaxf(sqrtf(wsum[0] + wsum[1]), 1e-8f);
    out[t]       = f2bf(x0 * sc);
    out[t + 128] = f2bf(x1 * sc);
    out[t + 256] = f2bf(x2 * sc);
}

// ---------------------------------------------------------------------------
// Kernel 1b: Q-side normalize into padded [100][208][384] buffer.
// ---------------------------------------------------------------------------
__global__ __launch_bounds__(128) void norm_q(const float* __restrict__ supq,
                                              const float* __restrict__ qry,
                                              unsigned short* __restrict__ dst) {
    int r = blockIdx.x;     // 0..207
    int img = blockIdx.y;   // 0..99
    unsigned short* out = dst + ((size_t)img * QROWS + r) * DIM;
    int t = threadIdx.x;
    if (r >= SEQ) {
        out[t] = 0; out[t + 128] = 0; out[t + 256] = 0;
        return;
    }
    const float* in = (img < NSUP)
        ? supq + ((size_t)img * SEQ + r) * DIM
        : qry  + ((size_t)(img - NSUP) * SEQ + r) * DIM;
    float x0 = in[t], x1 = in[t + 128], x2 = in[t + 256];
    float s = x0 * x0 + x1 * x1 + x2 * x2;
    #pragma unroll
    for (int off = 32; off; off >>= 1) s += __shfl_down(s, off);
    __shared__ float wsum[2];
    if ((t & 63) == 0) wsum[t >> 6] = s;
    __syncthreads();
    float sc = 1.0f / fmaxf(sqrtf(wsum[0] + wsum[1]), 1e-8f);
    out[t]       = f2bf(x0 * sc);
    out[t + 128] = f2bf(x1 * sc);
    out[t + 256] = f2bf(x2 * sc);
}

// ---------------------------------------------------------------------------
// Kernel 2: MFMA fused exp-sum GEMM, global_load_lds staging + XOR swizzle.
// Grid: flat 3900 blocks with bijective XCD remap (img-major chunks per XCD)
// so Kb (3.8 MB) stays L2-resident per XCD and Q panels are XCD-local.
// ---------------------------------------------------------------------------
#define MT  128
#define NTP 208
#define NTT 13
#define KCC 64

__device__ __forceinline__ void gload16(const void* g, void* l) {
    __builtin_amdgcn_global_load_lds(
        (__attribute__((address_space(1))) void*)g,
        (__attribute__((address_space(3))) void*)l, 16, 0, 0);
}

__global__ __launch_bounds__(256, 3) void fused_expsum_mfma(
    const unsigned short* __restrict__ Kb,     // [4992][384] bf16, pre /T
    const unsigned short* __restrict__ Qall,   // [100][208][384] bf16
    float* __restrict__ Rall)
{
    __shared__ __align__(16) unsigned short Asm[MT * KCC];    // 16 KiB
    __shared__ __align__(16) unsigned short Bsm[NTP * KCC];   // 26 KiB

    int t = threadIdx.x;

    // bijective XCD-aware remap (m204): NWG=3900, q=487, r=4
    int bid = blockIdx.x;
    int xcd = bid & 7;
    int sub = bid >> 3;
    const int qq = (MTILES * NIMG) >> 3;   // 487
    const int rr = (MTILES * NIMG) & 7;    // 4
    int L = (xcd < rr ? xcd * (qq + 1) : rr * (qq + 1) + (xcd - rr) * qq) + sub;
    int img = L / MTILES;
    int m_base = (L - img * MTILES) * MT;

    const unsigned short* Qimg = Qall + (size_t)img * (QROWS * DIM);

    int wv = t >> 6;        // wave 0..3
    int l  = t & 63;
    int lo = l & 15;        // MFMA frag row/col index
    int hi = l >> 4;        // k-group

    // staging: each global_load_lds writes 1024B = 8 rows x 128B, linear.
    // lane l covers (row = l>>3, 16B slot = l&7); source k-slot pre-swizzled.
    int srow = l >> 3;
    int skp  = (l & 7) ^ srow;      // involution within 8-slot row
    const unsigned short* aSrc = Kb   + (size_t)(m_base + wv * 32 + srow) * DIM + skp * 8;
    const unsigned short* bSrc = Qimg + (size_t)srow * DIM + skp * 8;

    v4f acc0[NTT], acc1[NTT];
    #pragma unroll
    for (int n = 0; n < NTT; ++n) {
        acc0[n] = (v4f){0.f, 0.f, 0.f, 0.f};
        acc1[n] = (v4f){0.f, 0.f, 0.f, 0.f};
    }

    for (int kb = 0; kb < DIM; kb += KCC) {
        // A: wave wv stages rows [wv*32, wv*32+32) as 4 x 8-row groups
        #pragma unroll
        for (int j = 0; j < 4; ++j)
            gload16(aSrc + (size_t)j * 8 * DIM + kb,
                    Asm + (wv * 32 + j * 8) * KCC);
        // B: 26 8-row groups round-robined over 4 waves
        #pragma unroll
        for (int jj = 0; jj < 7; ++jj) {
            int j = wv + jj * 4;
            if (j < 26)
                gload16(bSrc + (size_t)j * 8 * DIM + kb,
                        Bsm + j * 8 * KCC);
        }
        __syncthreads();   // drains vmcnt before LDS reads

        const unsigned short* Ar0 = Asm + (wv * 32 + lo) * KCC;
        const unsigned short* Br  = Bsm + lo * KCC;
        #pragma unroll
        for (int kk = 0; kk < 2; ++kk) {
            int koff = ((hi + 4 * kk) ^ (lo & 7)) * 8;   // swizzled k-slot
            v8s a0 = *(const v8s*)(Ar0 + koff);
            v8s a1 = *(const v8s*)(Ar0 + 16 * KCC + koff);
            #pragma unroll
            for (int n = 0; n < NTT; ++n) {
                v8s bb = *(const v8s*)(Br + n * 16 * KCC + koff);
                acc0[n] = __builtin_amdgcn_mfma_f32_16x16x32_bf16(a0, bb, acc0[n], 0, 0, 0);
                acc1[n] = __builtin_amdgcn_mfma_f32_16x16x32_bf16(a1, bb, acc1[n], 0, 0, 0);
            }
        }
        __syncthreads();
    }

    // epilogue: exp + sum over cols. C/D layout: col=lo, row=hi*4+reg.
    float s0[4] = {0.f, 0.f, 0.f, 0.f}, s1[4] = {0.f, 0.f, 0.f, 0.f};
    #pragma unroll
    for (int n = 0; n < NTT; ++n) {
        bool ok = (n * 16 + lo) < SEQ;
        #pragma unroll
        for (int j = 0; j < 4; ++j) {
            s0[j] += ok ? __expf(acc0[n][j]) : 0.f;
            s1[j] += ok ? __expf(acc1[n][j]) : 0.f;
        }
    }
    #pragma unroll
    for (int m = 1; m < 16; m <<= 1) {
        #pragma unroll
        for (int j = 0; j < 4; ++j) {
            s0[j] += __shfl_xor(s0[j], m);
            s1[j] += __shfl_xor(s1[j], m);
        }
    }
    if (lo == 0) {
        #pragma unroll
        for (int j = 0; j < 4; ++j) {
            int r0 = m_base + wv * 32 + hi * 4 + j;
            int r1 = r0 + 16;
            if (r0 < LSUP) {
                float o = s0[j];
                if (img < NSUP && (r0 / SEQ) == img) o = 0.f;
                Rall[(size_t)img * LSUP + r0] = o;
            }
            if (r1 < LSUP) {
                float o = s1[j];
                if (img < NSUP && (r1 / SEQ) == img) o = 0.f;
                Rall[(size_t)img * LSUP + r1] = o;
            }
        }
    }
}

// ---------------------------------------------------------------------------
// Kernel 3: fused optimizer (init + 15 SGD steps + final prediction).
// PLAIN launch, 10 blocks x 512. Cross-block sync via hand-rolled
// monotonic-counter barrier (device-scope atomics; ~1 us vs ~9 us for
// HIP grid.sync). 10 blocks on 256 CUs are always co-resident.
// Dbufs (16*125) + bar and out (375) are pre-zeroed via hipMemsetAsync.
// ---------------------------------------------------------------------------
__global__ __launch_bounds__(512) void opt_fused(
    const float* __restrict__ Rall,
    const int* __restrict__ labels,
    float* __restrict__ Dbufs,      // [16][125], pre-zeroed
    float* __restrict__ out,        // [75][5], pre-zeroed
    int* __restrict__ bar)          // barrier counter, pre-zeroed
{
    __shared__ float cfs[NSUP];
    __shared__ float red[8][NSUP];
    __shared__ float esm[512];

    int blk = blockIdx.x;           // 0..9
    int w = blk >> 1, h = blk & 1;
    int t = threadIdx.x;
    int wave = t >> 6, lane = t & 63;
    bool act = t < 490;
    int ls = w * BLOCK_W + h * 490 + t;

    int gen = 0;
    auto gridbar = [&]() {
        __syncthreads();            // compiler emits vmcnt(0) drain here
        if (t == 0) {
            ++gen;
            __hip_atomic_fetch_add(bar, 1, __ATOMIC_RELEASE, __HIP_MEMORY_SCOPE_AGENT);
            while (__hip_atomic_load(bar, __ATOMIC_ACQUIRE, __HIP_MEMORY_SCOPE_AGENT) < gen * 10) {}
        }
        __syncthreads();
    };

    float Rv[NSUP];
    #pragma unroll
    for (int b = 0; b < NSUP; ++b)
        Rv[b] = act ? Rall[(size_t)b * LSUP + ls] : 0.f;

    float vv = 0.f;
    float e  = 1.f;                 // e^{v/T}, v starts at 0

    // ---- D0 contribution (e = 1) ----
    {
        float part[NSUP];
        #pragma unroll
        for (int b = 0; b < NSUP; ++b) part[b] = Rv[b];
        #pragma unroll
        for (int b = 0; b < NSUP; ++b) {
            #pragma unroll
            for (int m = 32; m; m >>= 1) part[b] += __shfl_xor(part[b], m);
        }
        if (lane == 0) {
            #pragma unroll
            for (int b = 0; b < NSUP; ++b) red[wave][b] = part[b];
        }
        __syncthreads();
        if (t < NSUP) {
            float s = 0.f;
            #pragma unroll
            for (int wv2 = 0; wv2 < 8; ++wv2) s += red[wv2][t];
            atomicAdd(&Dbufs[t * 5 + w], s);
        }
    }

    // ---- SGD steps (barrier at step START; last step's D never needed) ----
    for (int s = 0; s < OPT_STEPS; ++s) {
        gridbar();
        const float* Dp = Dbufs + s * 125;
        if (t < NSUP) {
            int b = t;
            float Dsum = 0.f, Dw = 1.f;
            #pragma unroll
            for (int ww = 0; ww < 5; ++ww) {
                float d = Dp[b * 5 + ww];
                Dsum += d;
                if (ww == w) Dw = d;
            }
            int y = labels[b];
            cfs[b] = ((Dw / Dsum) - (w == y ? 1.f : 0.f)) * (INV_T / 25.f) / Dw;
        }
        __syncthreads();
        float g = 0.f;
        #pragma unroll
        for (int b = 0; b < NSUP; ++b) g += cfs[b] * Rv[b];
        if (act) {
            vv -= LR_F * e * g;
            e = __expf(vv * INV_T);
        }
        __syncthreads();            // protect red[] reuse across steps
        if (s + 1 < OPT_STEPS) {
            float part[NSUP];
            #pragma unroll
            for (int b = 0; b < NSUP; ++b) part[b] = e * Rv[b];   // inactive: Rv=0
            #pragma unroll
            for (int b = 0; b < NSUP; ++b) {
                #pragma unroll
                for (int m = 32; m; m >>= 1) part[b] += __shfl_xor(part[b], m);
            }
            if (lane == 0) {
                #pragma unroll
                for (int b = 0; b < NSUP; ++b) red[wave][b] = part[b];
            }
            __syncthreads();
            if (t < NSUP) {
                float s2 = 0.f;
                #pragma unroll
                for (int wv2 = 0; wv2 < 8; ++wv2) s2 += red[wv2][t];
                atomicAdd(&Dbufs[(s + 1) * 125 + t * 5 + w], s2);
            }
        }
    }

    // ---- final prediction, wave-parallel over qb ----
    esm[t] = act ? e : 0.f;
    __syncthreads();
    for (int qb = wave; qb < NQRY; qb += 8) {
        const float* R = Rall + (size_t)(NSUP + qb) * LSUP + w * BLOCK_W + h * 490;
        float p = 0.f;
        for (int i = lane; i < 490; i += 64) p += esm[i] * R[i];
        #pragma unroll
        for (int m = 32; m; m >>= 1) p += __shfl_xor(p, m);
        if (lane == 0) atomicAdd(&out[qb * 5 + w], p);
    }
    gridbar();
    if (blk == 0) {
        for (int i = t; i < NQRY * NW; i += 512) out[i] = logf(out[i]);
    }
}

// ---------------------------------------------------------------------------
extern "C" void kernel_launch(void* const* d_in, const int* in_sizes, int n_in,
                              void* d_out, int out_size, void* d_ws, size_t ws_size,
                              hipStream_t stream) {
    const float* sup_key = (const float*)d_in[0];   // [25,196,384]
    const float* sup_qry = (const float*)d_in[1];   // [25,196,384]
    const float* qry     = (const float*)d_in[2];   // [75,196,384]
    const int*   labels  = (const int*)d_in[3];     // [25]
    float* out = (float*)d_out;                     // [75,5]

    char* ws = (char*)d_ws;
    size_t off = 0;
    auto take = [&](size_t bytes) {
        char* p = ws + off;
        off = (off + bytes + 255) & ~(size_t)255;
        return p;
    };
    unsigned short* Kb   = (unsigned short*)take((size_t)LSUP_PAD * DIM * 2);
    unsigned short* Qall = (unsigned short*)take((size_t)NIMG * QROWS * DIM * 2);
    float*          Rall = (float*)take((size_t)NIMG * LSUP * 4);
    float*          Dbuf = (float*)take(((size_t)(OPT_STEPS + 1) * 125 + 64) * 4);
    int*            bar  = (int*)(Dbuf + (OPT_STEPS + 1) * 125);

    hipMemsetAsync(Dbuf, 0, ((size_t)(OPT_STEPS + 1) * 125 + 64) * 4, stream);
    hipMemsetAsync(out, 0, (size_t)NQRY * NW * 4, stream);

    norm_k<<<LSUP_PAD, 128, 0, stream>>>(sup_key, Kb);
    norm_q<<<dim3(QROWS, NIMG), 128, 0, stream>>>(sup_qry, qry, Qall);

    fused_expsum_mfma<<<MTILES * NIMG, 256, 0, stream>>>(Kb, Qall, Rall);

    opt_fused<<<10, 512, 0, stream>>>(Rall, labels, Dbuf, out, bar);
}